// Round 9
// baseline (665.347 us; speedup 1.0000x reference)
//
#include <hip/hip_runtime.h>
#include <hip/hip_bf16.h>

typedef float f32x4 __attribute__((ext_vector_type(4)));
typedef int   i32x4 __attribute__((ext_vector_type(4)));
typedef __bf16 bf16x8 __attribute__((ext_vector_type(8)));

#define BM 256
#define BN 256
#define SLAB 16384   // bytes per slab (A or B): 256 rows x 64 B
// bf16: 64 B/row = 32 k (KS=32). i8: 64 B/row = 64 k (KS=64). Same layout.

__device__ __forceinline__ unsigned short f2bf(float f) {
    unsigned int u = __float_as_uint(f);
    u += 0x7fffu + ((u >> 16) & 1u);
    return (unsigned short)(u >> 16);
}

__device__ __forceinline__ void load_lds16(const void* g, void* l) {
    __builtin_amdgcn_global_load_lds((const __attribute__((address_space(1))) void*)g,
                                     (__attribute__((address_space(3))) void*)l,
                                     16, 0, 0);
}

// ---------------- conversion kernels ----------------
__global__ void cvt_f32_to_i8_k(const float* __restrict__ in,
                                signed char* __restrict__ out, int n) {
    int stride = gridDim.x * blockDim.x;
    for (int i = blockIdx.x * blockDim.x + threadIdx.x; i * 8 < n; i += stride) {
        float4 v0 = *reinterpret_cast<const float4*>(in + (size_t)i * 8);
        float4 v1 = *reinterpret_cast<const float4*>(in + (size_t)i * 8 + 4);
        union { signed char c[8]; int2 w; } u;
        float s = 127.0f / 6.0f;
        float f[8] = {v0.x, v0.y, v0.z, v0.w, v1.x, v1.y, v1.z, v1.w};
#pragma unroll
        for (int j = 0; j < 8; ++j) {
            int q = __float2int_rn(f[j] * s);
            q = q > 127 ? 127 : (q < -127 ? -127 : q);
            u.c[j] = (signed char)q;
        }
        *reinterpret_cast<int2*>(out + (size_t)i * 8) = u.w;
    }
}

__global__ void cvt_i32_to_i8_k(const int* __restrict__ in,
                                signed char* __restrict__ out, int n,
                                const int* __restrict__ zp) {
    int z = zp[0];
    int stride = gridDim.x * blockDim.x;
    for (int i = blockIdx.x * blockDim.x + threadIdx.x; i * 8 < n; i += stride) {
        int4 v0 = *reinterpret_cast<const int4*>(in + (size_t)i * 8);
        int4 v1 = *reinterpret_cast<const int4*>(in + (size_t)i * 8 + 4);
        union { signed char c[8]; int2 w; } u;
        int f[8] = {v0.x, v0.y, v0.z, v0.w, v1.x, v1.y, v1.z, v1.w};
#pragma unroll
        for (int j = 0; j < 8; ++j) {
            int q = f[j] - z;
            q = q > 127 ? 127 : (q < -128 ? -128 : q);
            u.c[j] = (signed char)q;
        }
        *reinterpret_cast<int2*>(out + (size_t)i * 8) = u.w;
    }
}

__global__ void cvt_i32_to_bf16_k(const int* __restrict__ in,
                                  unsigned short* __restrict__ out, int n,
                                  const int* __restrict__ zp) {
    int z = zp[0];
    int stride = gridDim.x * blockDim.x;
    for (int i = blockIdx.x * blockDim.x + threadIdx.x; i * 4 < n; i += stride) {
        int4 v = *reinterpret_cast<const int4*>(in + (size_t)i * 4);
        ushort4 o = make_ushort4(f2bf((float)(v.x - z)), f2bf((float)(v.y - z)),
                                 f2bf((float)(v.z - z)), f2bf((float)(v.w - z)));
        *reinterpret_cast<ushort4*>(out + (size_t)i * 4) = o;
    }
}

// ---------------- GEMM skeleton: 4 waves, 128x128/wave, frag double-buffer --
// Ring-4 slabs, 3 prefetched ahead (24 loads/thread at prologue; 8/slab).
// Per kstep: vmcnt(8) publishes slab s+1's loads; barrier; ds_read frags(s+1)
// into the OTHER buffer; stage slab s+3; MFMA with CURRENT buffer (read last
// kstep) -> ds_reads overlap MFMAs within each wave (ILP). One barrier/kstep.
// Tail: vmcnt(8)/vmcnt(8)/vmcnt(0), final kstep = bare MFMA.

#define KREAD(SS, RA, RB, FRAGT)                                               \
    { const char* As_ = smem + ((SS) & 3) * SLAB;                              \
      const char* Bs_ = smem + 65536 + ((SS) & 3) * SLAB;                      \
      _Pragma("unroll") for (int m = 0; m < 8; ++m) {                          \
        int g = wr * 128 + m * 16 + l15;                                       \
        int rp = g >> 1;                                                       \
        int inner = ((g & 1) << 6) | kb;                                       \
        int off = rp * 128 + ((((inner >> 4) ^ rp) & 7) << 4);                 \
        RA[m] = *reinterpret_cast<const FRAGT*>(As_ + off);                    \
      }                                                                        \
      _Pragma("unroll") for (int n = 0; n < 8; ++n) {                          \
        int g = wc * 128 + n * 16 + l15;                                       \
        int rp = g >> 1;                                                       \
        int inner = ((g & 1) << 6) | kb;                                       \
        int off = rp * 128 + ((((inner >> 4) ^ rp) & 7) << 4);                 \
        RB[n] = *reinterpret_cast<const FRAGT*>(Bs_ + off);                    \
      }                                                                        \
    }

#define KSTEP_P(SS, VMSTR, DO_STAGE, RA, RB, CA, CB, FRAGT, MFMA)              \
  { asm volatile("s_waitcnt " VMSTR ::: "memory");                             \
    __builtin_amdgcn_s_barrier();                                              \
    KREAD((SS) + 1, RA, RB, FRAGT)                                             \
    if (DO_STAGE) { stageA((SS) + 3); stageB((SS) + 3); }                      \
    __builtin_amdgcn_s_setprio(1);                                             \
    _Pragma("unroll") for (int m = 0; m < 8; ++m)                              \
      _Pragma("unroll") for (int n = 0; n < 8; ++n)                            \
        acc[m][n] = MFMA(CA[m], CB[n], acc[m][n]);                             \
    __builtin_amdgcn_s_setprio(0);                                             \
  }

#define KFIN(CA, CB, MFMA)                                                     \
  { __builtin_amdgcn_s_setprio(1);                                             \
    _Pragma("unroll") for (int m = 0; m < 8; ++m)                              \
      _Pragma("unroll") for (int n = 0; n < 8; ++n)                            \
        acc[m][n] = MFMA(CA[m], CB[n], acc[m][n]);                             \
    __builtin_amdgcn_s_setprio(0);                                             \
  }

#define MFMA_BF16(aa, bb, cc) __builtin_amdgcn_mfma_f32_16x16x32_bf16(aa, bb, cc, 0, 0, 0)
#define MFMA_I8(aa, bb, cc)   __builtin_amdgcn_mfma_i32_16x16x64_i8(aa, bb, cc, 0, 0, 0)

// ---------------- GEMM1: h = gelu(dequant(xq * wfcq^T)+b) -------------------
__global__ __launch_bounds__(256, 1) void gemm_fc_i8(
    const signed char* __restrict__ A,   // xq [M,K] i8
    const signed char* __restrict__ Bt,  // wfcq [N,K] i8
    unsigned short* __restrict__ Cout,   // h bf16
    const int* __restrict__ bias_q,
    const float* __restrict__ s_w_p,
    const float* __restrict__ s_b_p,
    const int* __restrict__ z_b_p,
    int M, int N, int K)
{
    extern __shared__ char smem[];

    const int tid  = threadIdx.x;
    const int wave = tid >> 6;
    const int lane = tid & 63;
    const int wr = wave >> 1;        // 0..1
    const int wc = wave & 1;         // 0..1

    const int bid  = blockIdx.x;
    const int x8   = bid & 7;
    const int j32  = (bid >> 3) & 31;
    const int rnd  = bid >> 8;
    const int brow = (4 * x8 + (j32 >> 3)) * BM;
    const int bcol = (rnd * 8 + (j32 & 7)) * BN;

    const int NSLAB = K / 64;

    auto stageA = [&](int s) {
        char* base = smem + (s & 3) * SLAB;
#pragma unroll
        for (int h = 0; h < 4; ++h) {
            int p  = h * 256 + tid;
            int rp = p >> 3;
            int j  = (p & 7) ^ (rp & 7);
            const signed char* src =
                A + (size_t)(brow + 2 * rp + (j >> 2)) * K + s * 64 + (j & 3) * 16;
            void* dst = base + (h * 256 + wave * 64) * 16;
            load_lds16(src, dst);
        }
    };
    auto stageB = [&](int s) {
        char* base = smem + 65536 + (s & 3) * SLAB;
#pragma unroll
        for (int h = 0; h < 4; ++h) {
            int p  = h * 256 + tid;
            int rp = p >> 3;
            int j  = (p & 7) ^ (rp & 7);
            const signed char* src =
                Bt + (size_t)(bcol + 2 * rp + (j >> 2)) * K + s * 64 + (j & 3) * 16;
            void* dst = base + (h * 256 + wave * 64) * 16;
            load_lds16(src, dst);
        }
    };

    i32x4 acc[8][8] = {};
    i32x4 a0[8], b0[8], a1[8], b1[8];

    const int kb  = (lane >> 4) * 16;
    const int l15 = lane & 15;

    stageA(0); stageB(0);
    stageA(1); stageB(1);
    stageA(2); stageB(2);
    asm volatile("s_waitcnt vmcnt(16)" ::: "memory");
    __builtin_amdgcn_s_barrier();
    KREAD(0, a0, b0, i32x4)

    const int NL = NSLAB;   // 32
    for (int s = 0; s + 6 <= NL; s += 2) {
        KSTEP_P(s,     "vmcnt(8)", true, a1, b1, a0, b0, i32x4, MFMA_I8);
        KSTEP_P(s + 1, "vmcnt(8)", true, a0, b0, a1, b1, i32x4, MFMA_I8);
    }
    KSTEP_P(NL - 4, "vmcnt(8)", true,  a1, b1, a0, b0, i32x4, MFMA_I8);
    KSTEP_P(NL - 3, "vmcnt(8)", false, a0, b0, a1, b1, i32x4, MFMA_I8);
    KSTEP_P(NL - 2, "vmcnt(0)", false, a1, b1, a0, b0, i32x4, MFMA_I8);
    KFIN(a1, b1, MFMA_I8);

    // epilogue: dequant + bias + tanh-GELU -> bf16 via LDS, coalesced out
    const float s_w = s_w_p[0] * (6.0f / 127.0f);
    const float s_b = s_b_p[0];
    const int   z_b = z_b_p[0];

    __syncthreads();
    unsigned short* hl = (unsigned short*)smem;     // 256x256 bf16 = 128 KB
#pragma unroll
    for (int n = 0; n < 8; ++n) {
        int col_local = wc * 128 + n * 16 + l15;
        float bias = s_b * (float)(bias_q[bcol + col_local] - z_b);
        int c16 = col_local >> 3;
        int cb  = col_local & 7;
#pragma unroll
        for (int m = 0; m < 8; ++m) {
#pragma unroll
            for (int r = 0; r < 4; ++r) {
                int row_local = wr * 128 + m * 16 + (lane >> 4) * 4 + r;
                float v = (float)acc[m][n][r] * s_w + bias;
                float t2 = v * (1.5957691f + 0.0713548162f * v * v);
                float g  = v / (1.0f + __expf(-t2));
                int sw = c16 ^ (row_local & 31);
                hl[row_local * 256 + sw * 8 + cb] = f2bf(g);
            }
        }
    }
    __syncthreads();
#pragma unroll
    for (int it = 0; it < 32; ++it) {
        int lin = it * 256 + tid;      // 16B-chunk index, 0..8191
        int rl  = lin >> 5;
        int c16 = lin & 31;
        int sw  = c16 ^ (rl & 31);
        uint4 d = *reinterpret_cast<const uint4*>(hl + rl * 256 + sw * 8);
        *reinterpret_cast<uint4*>(Cout + (size_t)(brow + rl) * N + bcol + c16 * 8) = d;
    }
}

// ---------------- GEMM2: out = dequant(h * wproj^T)+b -----------------------
__global__ __launch_bounds__(256, 1) void gemm_proj(
    const unsigned short* __restrict__ A,
    const unsigned short* __restrict__ Bt,
    float* __restrict__ Cout,
    const int* __restrict__ bias_q,
    const float* __restrict__ s_w_p,
    const float* __restrict__ s_b_p,
    const int* __restrict__ z_b_p,
    int M, int N, int K)
{
    extern __shared__ char smem[];

    const int tid  = threadIdx.x;
    const int wave = tid >> 6;
    const int lane = tid & 63;
    const int wr = wave >> 1;
    const int wc = wave & 1;

    const int bid  = blockIdx.x;
    const int x8   = bid & 7;
    const int j32  = (bid >> 3) & 31;
    const int rnd  = bid >> 8;
    const int brow = (4 * x8 + (j32 >> 3)) * BM;
    const int bcol = (rnd * 8 + (j32 & 7)) * BN;

    const int NSLAB = K / 32;

    auto stageA = [&](int s) {
        char* base = smem + (s & 3) * SLAB;
#pragma unroll
        for (int h = 0; h < 4; ++h) {
            int p  = h * 256 + tid;
            int rp = p >> 3;
            int j  = (p & 7) ^ (rp & 7);
            const unsigned short* src =
                A + (size_t)(brow + 2 * rp + (j >> 2)) * K + s * 32 + (j & 3) * 8;
            void* dst = base + (h * 256 + wave * 64) * 16;
            load_lds16(src, dst);
        }
    };
    auto stageB = [&](int s) {
        char* base = smem + 65536 + (s & 3) * SLAB;
#pragma unroll
        for (int h = 0; h < 4; ++h) {
            int p  = h * 256 + tid;
            int rp = p >> 3;
            int j  = (p & 7) ^ (rp & 7);
            const unsigned short* src =
                Bt + (size_t)(bcol + 2 * rp + (j >> 2)) * K + s * 32 + (j & 3) * 8;
            void* dst = base + (h * 256 + wave * 64) * 16;
            load_lds16(src, dst);
        }
    };

    f32x4 acc[8][8] = {};
    bf16x8 a0[8], b0[8], a1[8], b1[8];

    const int kb  = (lane >> 4) * 16;
    const int l15 = lane & 15;

    stageA(0); stageB(0);
    stageA(1); stageB(1);
    stageA(2); stageB(2);
    asm volatile("s_waitcnt vmcnt(16)" ::: "memory");
    __builtin_amdgcn_s_barrier();
    KREAD(0, a0, b0, bf16x8)

    const int NL = NSLAB;   // 256
    for (int s = 0; s + 6 <= NL; s += 2) {
        KSTEP_P(s,     "vmcnt(8)", true, a1, b1, a0, b0, bf16x8, MFMA_BF16);
        KSTEP_P(s + 1, "vmcnt(8)", true, a0, b0, a1, b1, bf16x8, MFMA_BF16);
    }
    KSTEP_P(NL - 4, "vmcnt(8)", true,  a1, b1, a0, b0, bf16x8, MFMA_BF16);
    KSTEP_P(NL - 3, "vmcnt(8)", false, a0, b0, a1, b1, bf16x8, MFMA_BF16);
    KSTEP_P(NL - 2, "vmcnt(0)", false, a1, b1, a0, b0, bf16x8, MFMA_BF16);
    KFIN(a1, b1, MFMA_BF16);

    const float s_w = s_w_p[0];
    const float s_b = s_b_p[0];
    const int   z_b = z_b_p[0];
    const int row0 = brow + wr * 128;
    const int col0 = bcol + wc * 128;
#pragma unroll
    for (int n = 0; n < 8; ++n) {
        int col = col0 + n * 16 + l15;
        float bias = s_b * (float)(bias_q[col] - z_b);
#pragma unroll
        for (int m = 0; m < 8; ++m) {
#pragma unroll
            for (int r = 0; r < 4; ++r) {
                int row = row0 + m * 16 + (lane >> 4) * 4 + r;
                Cout[(size_t)row * N + col] = acc[m][n][r] * s_w + bias;
            }
        }
    }
}

extern "C" void kernel_launch(void* const* d_in, const int* in_sizes, int n_in,
                              void* d_out, int out_size, void* d_ws, size_t ws_size,
                              hipStream_t stream) {
    const float* x        = (const float*)d_in[0];
    const int*   w_fc_q   = (const int*)d_in[1];
    const int*   b_fc_q   = (const int*)d_in[2];
    const int*   w_proj_q = (const int*)d_in[3];
    const int*   b_proj_q = (const int*)d_in[4];
    const float* s_fc_w   = (const float*)d_in[5];
    const float* s_fc_b   = (const float*)d_in[6];
    const float* s_proj_w = (const float*)d_in[7];
    const float* s_proj_b = (const float*)d_in[8];
    const int*   z_fc_w   = (const int*)d_in[9];
    const int*   z_fc_b   = (const int*)d_in[10];
    const int*   z_proj_w = (const int*)d_in[11];
    const int*   z_proj_b = (const int*)d_in[12];

    const int M = 4 * 2048;
    const int E = 2048;
    const int H = 4 * 2048;

    // ws: xq i8 [M*E] | wfcq i8 [H*E] | wproj bf16 [E*H] | hb bf16 [M*H]
    size_t need = (size_t)M * E + (size_t)H * E
                + ((size_t)E * H + (size_t)M * H) * 2;
    if (ws_size < need) return;

    signed char*    xq    = (signed char*)d_ws;
    signed char*    wfcq  = xq + (size_t)M * E;
    unsigned short* wproj = (unsigned short*)(wfcq + (size_t)H * E);
    unsigned short* hb    = wproj + (size_t)E * H;

    hipFuncSetAttribute(reinterpret_cast<const void*>(gemm_fc_i8),
                        hipFuncAttributeMaxDynamicSharedMemorySize, 131072);
    hipFuncSetAttribute(reinterpret_cast<const void*>(gemm_proj),
                        hipFuncAttributeMaxDynamicSharedMemorySize, 131072);

    cvt_f32_to_i8_k<<<2048, 256, 0, stream>>>(x, xq, M * E);
    cvt_i32_to_i8_k<<<2048, 256, 0, stream>>>(w_fc_q, wfcq, H * E, z_fc_w);
    cvt_i32_to_bf16_k<<<2048, 256, 0, stream>>>(w_proj_q, wproj, E * H, z_proj_w);

    // GEMM1: i8 MFMA (exact int32 accum), fused dequant+bias+GELU -> bf16 h
    gemm_fc_i8<<<dim3((M / BM) * (H / BN)), 256, 131072, stream>>>(
        xq, wfcq, hb, b_fc_q, s_fc_w, s_fc_b, z_fc_b, M, H, E);

    // GEMM2: bf16 MFMA ; scale+bias -> f32 out
    gemm_proj<<<dim3((M / BM) * (E / BN)), 256, 131072, stream>>>(
        hb, wproj, (float*)d_out, b_proj_q, s_proj_w, s_proj_b, z_proj_b, M, E, H);
}

// Round 10
// 425.417 us; speedup vs baseline: 1.5640x; 1.5640x over previous
//
#include <hip/hip_runtime.h>
#include <hip/hip_bf16.h>

typedef float f32x4 __attribute__((ext_vector_type(4)));
typedef int   i32x4 __attribute__((ext_vector_type(4)));
typedef __bf16 bf16x8 __attribute__((ext_vector_type(8)));

#define BM 256
#define BN 256
#define SLAB 16384   // bytes per slab (A or B): 256 rows x 64 B
// bf16: 64 B/row = 32 k (KS=32). i8: 64 B/row = 64 k (KS=64). Same byte layout,
// same 64 B/kstep source advance for both dtypes.

__device__ __forceinline__ unsigned short f2bf(float f) {
    unsigned int u = __float_as_uint(f);
    u += 0x7fffu + ((u >> 16) & 1u);
    return (unsigned short)(u >> 16);
}

__device__ __forceinline__ void load_lds16(const void* g, void* l) {
    __builtin_amdgcn_global_load_lds((const __attribute__((address_space(1))) void*)g,
                                     (__attribute__((address_space(3))) void*)l,
                                     16, 0, 0);
}

// ---------------- conversion kernels ----------------
__global__ void cvt_f32_to_i8_k(const float* __restrict__ in,
                                signed char* __restrict__ out, int n) {
    int stride = gridDim.x * blockDim.x;
    for (int i = blockIdx.x * blockDim.x + threadIdx.x; i * 8 < n; i += stride) {
        float4 v0 = *reinterpret_cast<const float4*>(in + (size_t)i * 8);
        float4 v1 = *reinterpret_cast<const float4*>(in + (size_t)i * 8 + 4);
        union { signed char c[8]; int2 w; } u;
        float s = 127.0f / 6.0f;
        float f[8] = {v0.x, v0.y, v0.z, v0.w, v1.x, v1.y, v1.z, v1.w};
#pragma unroll
        for (int j = 0; j < 8; ++j) {
            int q = __float2int_rn(f[j] * s);
            q = q > 127 ? 127 : (q < -127 ? -127 : q);
            u.c[j] = (signed char)q;
        }
        *reinterpret_cast<int2*>(out + (size_t)i * 8) = u.w;
    }
}

__global__ void cvt_i32_to_i8_k(const int* __restrict__ in,
                                signed char* __restrict__ out, int n,
                                const int* __restrict__ zp) {
    int z = zp[0];
    int stride = gridDim.x * blockDim.x;
    for (int i = blockIdx.x * blockDim.x + threadIdx.x; i * 8 < n; i += stride) {
        int4 v0 = *reinterpret_cast<const int4*>(in + (size_t)i * 8);
        int4 v1 = *reinterpret_cast<const int4*>(in + (size_t)i * 8 + 4);
        union { signed char c[8]; int2 w; } u;
        int f[8] = {v0.x, v0.y, v0.z, v0.w, v1.x, v1.y, v1.z, v1.w};
#pragma unroll
        for (int j = 0; j < 8; ++j) {
            int q = f[j] - z;
            q = q > 127 ? 127 : (q < -128 ? -128 : q);
            u.c[j] = (signed char)q;
        }
        *reinterpret_cast<int2*>(out + (size_t)i * 8) = u.w;
    }
}

__global__ void cvt_i32_to_bf16_k(const int* __restrict__ in,
                                  unsigned short* __restrict__ out, int n,
                                  const int* __restrict__ zp) {
    int z = zp[0];
    int stride = gridDim.x * blockDim.x;
    for (int i = blockIdx.x * blockDim.x + threadIdx.x; i * 4 < n; i += stride) {
        int4 v = *reinterpret_cast<const int4*>(in + (size_t)i * 4);
        ushort4 o = make_ushort4(f2bf((float)(v.x - z)), f2bf((float)(v.y - z)),
                                 f2bf((float)(v.z - z)), f2bf((float)(v.w - z)));
        *reinterpret_cast<ushort4*>(out + (size_t)i * 4) = o;
    }
}

// ---------------- GEMM skeleton (round-8 schedule + strength reduction) -----
// 8 waves, 128x64 per wave. Ring-4 slabs, 3 ahead, counted vmcnt(8), tail
// vmcnt(4)/vmcnt(0). ONE barrier per kstep (round-8: inner barriers were dead
// scaffolding). Round-10: all per-kstep addressing is loop-invariant-hoisted:
// ds_read offsets precomputed (offA[8], offB[4]); staging sources are 4
// running pointers += 64 B; only SALU ring-base math remains in-loop.

// PRE: computes invariant offsets + staging pointers. ELEMB = bytes/elem of
// the staged matrix row (A row stride = K*ELEMB bytes).
#define GEMM_PRE(ATYPE, BTYPE)                                                 \
    const int kb  = (lane >> 4) * 16;                                          \
    const int l15 = lane & 15;                                                 \
    int offA[8], offB[4];                                                      \
    _Pragma("unroll") for (int m = 0; m < 8; ++m) {                            \
        int g = wr * 128 + m * 16 + l15;                                       \
        int rp = g >> 1;                                                       \
        int inner = ((g & 1) << 6) | kb;                                       \
        offA[m] = rp * 128 + ((((inner >> 4) ^ rp) & 7) << 4);                 \
    }                                                                          \
    _Pragma("unroll") for (int n = 0; n < 4; ++n) {                            \
        int g = wc * 64 + n * 16 + l15;                                        \
        int rp = g >> 1;                                                       \
        int inner = ((g & 1) << 6) | kb;                                       \
        offB[n] = rp * 128 + ((((inner >> 4) ^ rp) & 7) << 4);                 \
    }                                                                          \
    const int dA0 = wave * 1024, dA1 = 8192 + wave * 1024;                     \
    const char *pA0, *pA1, *pB0, *pB1;                                         \
    {                                                                          \
        int p0 = tid, p1 = 512 + tid;                                          \
        int rp0 = p0 >> 3, j0 = (p0 & 7) ^ (rp0 & 7);                          \
        int rp1 = p1 >> 3, j1 = (p1 & 7) ^ (rp1 & 7);                          \
        pA0 = (const char*)A + (size_t)(brow + 2 * rp0 + (j0 >> 2)) * rowbA    \
              + (j0 & 3) * 16 + 192;                                           \
        pA1 = (const char*)A + (size_t)(brow + 2 * rp1 + (j1 >> 2)) * rowbA    \
              + (j1 & 3) * 16 + 192;                                           \
        pB0 = (const char*)Bt + (size_t)(bcol + 2 * rp0 + (j0 >> 2)) * rowbB   \
              + (j0 & 3) * 16 + 192;                                           \
        pB1 = (const char*)Bt + (size_t)(bcol + 2 * rp1 + (j1 >> 2)) * rowbB   \
              + (j1 & 3) * 16 + 192;                                           \
    }                                                                          \
    /* prologue: stage slabs 0,1,2 (pointers sit at slab 3) */                 \
    _Pragma("unroll") for (int s = 0; s < 3; ++s) {                            \
        char* da = smem + s * SLAB;                                            \
        char* db = smem + 65536 + s * SLAB;                                    \
        load_lds16(pA0 + s * 64 - 192, da + dA0);                              \
        load_lds16(pA1 + s * 64 - 192, da + dA1);                              \
        load_lds16(pB0 + s * 64 - 192, db + dA0);                              \
        load_lds16(pB1 + s * 64 - 192, db + dA1);                              \
    }

#define KSTEP_R(SS, VMSTR, DO_STAGE, FRAGT, MFMA)                              \
  { asm volatile("s_waitcnt " VMSTR ::: "memory");                             \
    __builtin_amdgcn_s_barrier();                                              \
    const int sb = ((SS) & 3) << 14;                                           \
    const int db = (((SS) + 3) & 3) << 14;                                     \
    const char* As = smem + sb;                                                \
    const char* Bs = smem + 65536 + sb;                                        \
    FRAGT a[4], b[4];                                                          \
    _Pragma("unroll") for (int m = 0; m < 4; ++m)                              \
        a[m] = *reinterpret_cast<const FRAGT*>(As + offA[m]);                  \
    _Pragma("unroll") for (int n = 0; n < 4; ++n)                              \
        b[n] = *reinterpret_cast<const FRAGT*>(Bs + offB[n]);                  \
    if (DO_STAGE) {                                                            \
        load_lds16(pA0, smem + db + dA0);                                      \
        load_lds16(pA1, smem + db + dA1);                                      \
    }                                                                          \
    __builtin_amdgcn_s_setprio(1);                                             \
    _Pragma("unroll") for (int m = 0; m < 4; ++m)                              \
      _Pragma("unroll") for (int n = 0; n < 4; ++n)                            \
        acc[m][n] = MFMA(a[m], b[n], acc[m][n]);                               \
    __builtin_amdgcn_s_setprio(0);                                             \
    _Pragma("unroll") for (int m = 0; m < 4; ++m)                              \
        a[m] = *reinterpret_cast<const FRAGT*>(As + offA[m + 4]);              \
    if (DO_STAGE) {                                                            \
        load_lds16(pB0, smem + 65536 + db + dA0);                              \
        load_lds16(pB1, smem + 65536 + db + dA1);                              \
        pA0 += 64; pA1 += 64; pB0 += 64; pB1 += 64;                            \
    }                                                                          \
    __builtin_amdgcn_s_setprio(1);                                             \
    _Pragma("unroll") for (int m = 0; m < 4; ++m)                              \
      _Pragma("unroll") for (int n = 0; n < 4; ++n)                            \
        acc[m + 4][n] = MFMA(a[m], b[n], acc[m + 4][n]);                       \
    __builtin_amdgcn_s_setprio(0);                                             \
  }

#define MFMA_BF16(aa, bb, cc) __builtin_amdgcn_mfma_f32_16x16x32_bf16(aa, bb, cc, 0, 0, 0)
#define MFMA_I8(aa, bb, cc)   __builtin_amdgcn_mfma_i32_16x16x64_i8(aa, bb, cc, 0, 0, 0)

// ---------------- GEMM1: h = gelu(dequant(xq * wfcq^T)+b) -------------------
__global__ __launch_bounds__(512, 2) void gemm_fc_i8(
    const signed char* __restrict__ A,   // xq [M,K] i8
    const signed char* __restrict__ Bt,  // wfcq [N,K] i8
    unsigned short* __restrict__ Cout,   // h bf16
    const int* __restrict__ bias_q,
    const float* __restrict__ s_w_p,
    const float* __restrict__ s_b_p,
    const int* __restrict__ z_b_p,
    int M, int N, int K)
{
    extern __shared__ char smem[];

    const int tid  = threadIdx.x;
    const int wave = tid >> 6;
    const int lane = tid & 63;
    const int wr = wave >> 2;
    const int wc = wave & 3;

    const int bid  = blockIdx.x;
    const int x8   = bid & 7;
    const int j32  = (bid >> 3) & 31;
    const int rnd  = bid >> 8;
    const int brow = (4 * x8 + (j32 >> 3)) * BM;
    const int bcol = (rnd * 8 + (j32 & 7)) * BN;

    const int NSLAB = K / 64;            // 64 i8 per slab-row
    const size_t rowbA = (size_t)K;      // bytes per A row
    const size_t rowbB = (size_t)K;      // bytes per B row

    i32x4 acc[8][4] = {};

    GEMM_PRE(signed char, signed char)

    for (int s = 0; s < NSLAB - 2; ++s) {
        KSTEP_R(s, "vmcnt(8)", (s + 3 < NSLAB), i32x4, MFMA_I8);
    }
    KSTEP_R(NSLAB - 2, "vmcnt(4)", false, i32x4, MFMA_I8);
    KSTEP_R(NSLAB - 1, "vmcnt(0)", false, i32x4, MFMA_I8);

    // epilogue: dequant + bias + tanh-GELU -> bf16 via LDS, coalesced out
    const float s_w = s_w_p[0] * (6.0f / 127.0f);
    const float s_b = s_b_p[0];
    const int   z_b = z_b_p[0];

    __syncthreads();
    unsigned short* hl = (unsigned short*)smem;     // 256x256 bf16 = 128 KB
#pragma unroll
    for (int n = 0; n < 4; ++n) {
        int col_local = wc * 64 + n * 16 + l15;
        float bias = s_b * (float)(bias_q[bcol + col_local] - z_b);
        int c16 = col_local >> 3;
        int cb  = col_local & 7;
#pragma unroll
        for (int m = 0; m < 8; ++m) {
#pragma unroll
            for (int r = 0; r < 4; ++r) {
                int row_local = wr * 128 + m * 16 + (lane >> 4) * 4 + r;
                float v = (float)acc[m][n][r] * s_w + bias;
                float t2 = v * (1.5957691f + 0.0713548162f * v * v);
                float g  = v / (1.0f + __expf(-t2));
                int sw = c16 ^ (row_local & 31);
                hl[row_local * 256 + sw * 8 + cb] = f2bf(g);
            }
        }
    }
    __syncthreads();
#pragma unroll
    for (int it = 0; it < 16; ++it) {
        int lin = it * 512 + tid;      // 16B-chunk index, 0..8191
        int rl  = lin >> 5;
        int c16 = lin & 31;
        int sw  = c16 ^ (rl & 31);
        uint4 d = *reinterpret_cast<const uint4*>(hl + rl * 256 + sw * 8);
        *reinterpret_cast<uint4*>(Cout + (size_t)(brow + rl) * N + bcol + c16 * 8) = d;
    }
}

// ---------------- GEMM2: out = dequant(h * wproj^T)+b -----------------------
__global__ __launch_bounds__(512, 2) void gemm_proj(
    const unsigned short* __restrict__ A,
    const unsigned short* __restrict__ Bt,
    float* __restrict__ Cout,
    const int* __restrict__ bias_q,
    const float* __restrict__ s_w_p,
    const float* __restrict__ s_b_p,
    const int* __restrict__ z_b_p,
    int M, int N, int K)
{
    extern __shared__ char smem[];

    const int tid  = threadIdx.x;
    const int wave = tid >> 6;
    const int lane = tid & 63;
    const int wr = wave >> 2;
    const int wc = wave & 3;

    const int bid  = blockIdx.x;
    const int x8   = bid & 7;
    const int j32  = (bid >> 3) & 31;
    const int rnd  = bid >> 8;
    const int brow = (4 * x8 + (j32 >> 3)) * BM;
    const int bcol = (rnd * 8 + (j32 & 7)) * BN;

    const int NSLAB = K / 32;            // 32 bf16 per slab-row
    const size_t rowbA = (size_t)K * 2;
    const size_t rowbB = (size_t)K * 2;

    f32x4 acc[8][4] = {};

    GEMM_PRE(unsigned short, unsigned short)

    for (int s = 0; s < NSLAB - 2; ++s) {
        KSTEP_R(s, "vmcnt(8)", (s + 3 < NSLAB), bf16x8, MFMA_BF16);
    }
    KSTEP_R(NSLAB - 2, "vmcnt(4)", false, bf16x8, MFMA_BF16);
    KSTEP_R(NSLAB - 1, "vmcnt(0)", false, bf16x8, MFMA_BF16);

    const float s_w = s_w_p[0];
    const float s_b = s_b_p[0];
    const int   z_b = z_b_p[0];
    const int row0 = brow + wr * 128;
    const int col0 = bcol + wc * 64;
#pragma unroll
    for (int n = 0; n < 4; ++n) {
        int col = col0 + n * 16 + l15;
        float bias = s_b * (float)(bias_q[col] - z_b);
#pragma unroll
        for (int m = 0; m < 8; ++m) {
#pragma unroll
            for (int r = 0; r < 4; ++r) {
                int row = row0 + m * 16 + (lane >> 4) * 4 + r;
                Cout[(size_t)row * N + col] = acc[m][n][r] * s_w + bias;
            }
        }
    }
}

extern "C" void kernel_launch(void* const* d_in, const int* in_sizes, int n_in,
                              void* d_out, int out_size, void* d_ws, size_t ws_size,
                              hipStream_t stream) {
    const float* x        = (const float*)d_in[0];
    const int*   w_fc_q   = (const int*)d_in[1];
    const int*   b_fc_q   = (const int*)d_in[2];
    const int*   w_proj_q = (const int*)d_in[3];
    const int*   b_proj_q = (const int*)d_in[4];
    const float* s_fc_w   = (const float*)d_in[5];
    const float* s_fc_b   = (const float*)d_in[6];
    const float* s_proj_w = (const float*)d_in[7];
    const float* s_proj_b = (const float*)d_in[8];
    const int*   z_fc_w   = (const int*)d_in[9];
    const int*   z_fc_b   = (const int*)d_in[10];
    const int*   z_proj_w = (const int*)d_in[11];
    const int*   z_proj_b = (const int*)d_in[12];

    const int M = 4 * 2048;
    const int E = 2048;
    const int H = 4 * 2048;

    // ws: xq i8 [M*E] | wfcq i8 [H*E] | wproj bf16 [E*H] | hb bf16 [M*H]
    size_t need = (size_t)M * E + (size_t)H * E
                + ((size_t)E * H + (size_t)M * H) * 2;
    if (ws_size < need) return;

    signed char*    xq    = (signed char*)d_ws;
    signed char*    wfcq  = xq + (size_t)M * E;
    unsigned short* wproj = (unsigned short*)(wfcq + (size_t)H * E);
    unsigned short* hb    = wproj + (size_t)E * H;

    hipFuncSetAttribute(reinterpret_cast<const void*>(gemm_fc_i8),
                        hipFuncAttributeMaxDynamicSharedMemorySize, 131072);
    hipFuncSetAttribute(reinterpret_cast<const void*>(gemm_proj),
                        hipFuncAttributeMaxDynamicSharedMemorySize, 131072);

    cvt_f32_to_i8_k<<<2048, 256, 0, stream>>>(x, xq, M * E);
    cvt_i32_to_i8_k<<<2048, 256, 0, stream>>>(w_fc_q, wfcq, H * E, z_fc_w);
    cvt_i32_to_bf16_k<<<2048, 256, 0, stream>>>(w_proj_q, wproj, E * H, z_proj_w);

    // GEMM1: i8 MFMA (exact int32 accum), fused dequant+bias+GELU -> bf16 h
    gemm_fc_i8<<<dim3((M / BM) * (H / BN)), 512, 131072, stream>>>(
        xq, wfcq, hb, b_fc_q, s_fc_w, s_fc_b, z_fc_b, M, H, E);

    // GEMM2: bf16 MFMA ; scale+bias -> f32 out
    gemm_proj<<<dim3((M / BM) * (E / BN)), 512, 131072, stream>>>(
        hb, wproj, (float*)d_out, b_proj_q, s_proj_w, s_proj_b, z_proj_b, M, E, H);
}